// Round 6
// baseline (124.059 us; speedup 1.0000x reference)
//
#include <hip/hip_runtime.h>
#include <math.h>

#define NJ   24
#define TPB  256
#define IPB  64     // items per block
#define IPG  16     // items per group
#define NG   4      // groups per block
#define IST  73     // float4 stride per item in LDS (24*3 + 1 pad)

static constexpr int PAR[NJ] = {-1,0,0,0,1,2,3,4,5,6,7,8,9,9,9,12,13,14,16,17,18,19,20,21};

__global__ __launch_bounds__(TPB) void fk_kernel(
    const float* __restrict__ theta,        // Bn*NJ*3
    const float* __restrict__ rest_pose,    // NJ*3
    const float* __restrict__ bone_factor,  // NJ-1
    float* __restrict__ kp3d,               // Bn*NJ*3
    float* __restrict__ orient,             // Bn*NJ*9
    float* __restrict__ l2ws,               // Bn*NJ*16
    int Bn)
{
    __shared__ float4 ls[IPG * IST];        // 18,688 B

    const int tid   = threadIdx.x;
    const int item0 = blockIdx.x * IPB;
    if (item0 >= Bn) return;

    float4* l2g = reinterpret_cast<float4*>(l2ws);
    float4* org = reinterpret_cast<float4*>(orient);
    float4* kpg = reinterpret_cast<float4*>(kp3d);
    const float* lf = reinterpret_cast<const float*>(ls);

    for (int g = 0; g < NG; ++g) {
        __syncthreads();   // previous group's flush done before overwrite

        // ---------- produce: wave 0, lane (it,row) owns one matrix row ----------
        if (tid < 64) {
            const int it  = tid >> 2;
            const int row = tid & 3;
            const int gi  = item0 + g * IPG + it;
            if (row < 3 && gi < Bn) {
                const float* th = theta + (size_t)gi * (NJ * 3);
                float4 rows[NJ];            // static-indexed; compiler prunes dead
                #pragma unroll
                for (int j = 0; j < NJ; ++j) {
                    const float x = th[j*3+0], y = th[j*3+1], z = th[j*3+2];
                    const float ang = sqrtf(x*x + y*y + z*z + 1e-12f);
                    const float inv = 1.0f / ang;
                    const float ux = x*inv, uy = y*inv, uz = z*inv;
                    const float s  = __sinf(ang);
                    const float cs = __cosf(ang);
                    const float ic = 1.0f - cs;
                    const float xx = ic*ux*ux, yy = ic*uy*uy, zz = ic*uz*uz;
                    const float xy = ic*ux*uy, xz = ic*ux*uz, yz = ic*uy*uz;
                    const float sx = s*ux, sy = s*uy, sz = s*uz;
                    const float R00 = cs+xx,  R01 = xy-sz, R02 = xz+sy;
                    const float R10 = xy+sz,  R11 = cs+yy, R12 = yz-sx;
                    const float R20 = xz-sy,  R21 = yz+sx, R22 = cs+zz;

                    float4 p; float bx, by, bz;
                    if (j == 0) {
                        p = make_float4(row == 0 ? 1.f : 0.f,
                                        row == 1 ? 1.f : 0.f,
                                        row == 2 ? 1.f : 0.f, 0.f);
                        bx = rest_pose[0]; by = rest_pose[1]; bz = rest_pose[2];
                    } else {
                        p = rows[PAR[j]];
                        float bf = bone_factor[j - 1];
                        bf = sqrtf(bf*bf + 1e-36f);
                        bx = (rest_pose[j*3+0] - rest_pose[PAR[j]*3+0]) * bf;
                        by = (rest_pose[j*3+1] - rest_pose[PAR[j]*3+1]) * bf;
                        bz = (rest_pose[j*3+2] - rest_pose[PAR[j]*3+2]) * bf;
                    }
                    float4 nr;
                    nr.x = p.x*R00 + p.y*R10 + p.z*R20;
                    nr.y = p.x*R01 + p.y*R11 + p.z*R21;
                    nr.z = p.x*R02 + p.y*R12 + p.z*R22;
                    nr.w = p.x*bx  + p.y*by  + p.z*bz + p.w;
                    rows[j] = nr;
                    ls[it * IST + j * 3 + row] = nr;
                }
            }
        }
        __syncthreads();

        // ---------- flush: all 256 lanes, every byte exactly once, aligned ----
        const int gbase = item0 + g * IPG;

        // l2ws: 1536 f4 contiguous (16 items x 1536 B), 6 exact rounds
        {
            float4* dst = l2g + (size_t)gbase * 96;
            #pragma unroll
            for (int k = 0; k < 6; ++k) {
                const int q  = k * TPB + tid;          // [0,1536)
                const int it = q / 96, off = q % 96;
                const int jj = off >> 2, rr = off & 3;
                float4 v;
                if (rr == 3) v = make_float4(0.f, 0.f, 0.f, 1.f);
                else         v = ls[it * IST + jj * 3 + rr];
                if (gbase + it < Bn) dst[q] = v;
            }
        }
        // orient: 864 f4 contiguous (16 x 864 B, 128B-aligned span)
        {
            float4* dst = org + (size_t)gbase * 54;
            #pragma unroll
            for (int k = 0; k < 4; ++k) {
                const int q = k * TPB + tid;
                if (q < 864) {
                    float v[4];
                    #pragma unroll
                    for (int m = 0; m < 4; ++m) {
                        const int f  = q * 4 + m;      // [0,3456)
                        const int it = f / 216, r2 = f % 216;
                        const int jj = r2 / 9,  mm = r2 % 9;
                        v[m] = lf[(it * IST + jj * 3 + mm / 3) * 4 + mm % 3];
                    }
                    if (gbase + q / 54 < Bn)
                        dst[q] = make_float4(v[0], v[1], v[2], v[3]);
                }
            }
        }
        // kp3d: 288 f4 contiguous (16 x 288 B, 128B-aligned span)
        {
            float4* dst = kpg + (size_t)gbase * 18;
            #pragma unroll
            for (int k = 0; k < 2; ++k) {
                const int q = k * TPB + tid;
                if (q < 288) {
                    float v[4];
                    #pragma unroll
                    for (int m = 0; m < 4; ++m) {
                        const int f  = q * 4 + m;      // [0,1152)
                        const int it = f / 72, r2 = f % 72;
                        const int jj = r2 / 3, rw = r2 % 3;
                        v[m] = lf[(it * IST + jj * 3 + rw) * 4 + 3];
                    }
                    if (gbase + q / 18 < Bn)
                        dst[q] = make_float4(v[0], v[1], v[2], v[3]);
                }
            }
        }
    }
}

extern "C" void kernel_launch(void* const* d_in, const int* in_sizes, int n_in,
                              void* d_out, int out_size, void* d_ws, size_t ws_size,
                              hipStream_t stream) {
    const float* theta       = (const float*)d_in[0];
    const float* rest_pose   = (const float*)d_in[1];
    const float* bone_factor = (const float*)d_in[2];

    const int Bn = in_sizes[0] / (NJ * 3);
    const size_t BNJ = (size_t)Bn * NJ;

    float* out    = (float*)d_out;
    float* kp3d   = out;                // BNJ*3
    float* orient = out + BNJ * 3;      // BNJ*9
    float* l2ws   = out + BNJ * 12;     // BNJ*16

    const int grid = (Bn + IPB - 1) / IPB;
    fk_kernel<<<grid, TPB, 0, stream>>>(theta, rest_pose, bone_factor,
                                        kp3d, orient, l2ws, Bn);
}

// Round 7
// 113.385 us; speedup vs baseline: 1.0941x; 1.0941x over previous
//
#include <hip/hip_runtime.h>
#include <math.h>

#define NJ   24
#define TPB  256
#define IPB  64     // items per block (= lanes per wave)
#define CJ   8      // joints per chunk
#define NCH  3      // chunks
#define ROW  33     // float4 stride per item in LDS (32 + 1 pad)

static constexpr int PAR[NJ] = {-1,0,0,0,1,2,3,4,5,6,7,8,9,9,9,12,13,14,16,17,18,19,20,21};

__global__ __launch_bounds__(TPB, 4) void fk_kernel(
    const float* __restrict__ theta,        // Bn*NJ*3
    const float* __restrict__ rest_pose,    // NJ*3
    const float* __restrict__ bone_factor,  // NJ-1
    float* __restrict__ kp3d,               // Bn*NJ*3
    float* __restrict__ orient,             // Bn*NJ*9
    float* __restrict__ l2ws,               // Bn*NJ*16
    int Bn)
{
    __shared__ float4 ls[IPB * ROW];        // 33,792 B

    const int tid   = threadIdx.x;
    const int w     = tid >> 6;             // wave = matrix row (0..3)
    const int lane  = tid & 63;             // lane = item within block
    const int item0 = blockIdx.x * IPB;
    if (item0 >= Bn) return;
    const int n_i = min(IPB, Bn - item0);
    const int b   = item0 + lane;

    float4* l2g = reinterpret_cast<float4*>(l2ws);
    float4* org = reinterpret_cast<float4*>(orient);
    float4* kpg = reinterpret_cast<float4*>(kp3d);
    const float* lf = reinterpret_cast<const float*>(ls);

    // chain state: this lane's row `w` of each joint's [R|t]; constant-indexed.
    float4 rows[NJ];

    #pragma unroll
    for (int c = 0; c < NCH; ++c) {
        // ---------- compute: waves 0-2 = rows 0-2 of all 64 items; wave 3 = bottom rows
        if (w == 3) {
            #pragma unroll
            for (int jj = 0; jj < CJ; ++jj)
                ls[lane * ROW + jj * 4 + 3] = make_float4(0.f, 0.f, 0.f, 1.f);
        } else if (b < Bn) {
            // chunk theta: 24 floats = 6 float4, coalesced (288 B item stride)
            float t[CJ * 3];
            {
                const float4* tb4 = reinterpret_cast<const float4*>(theta);
                const int base = b * 18 + c * 6;    // float4 index
                #pragma unroll
                for (int i = 0; i < 6; ++i) {
                    const float4 v = tb4[base + i];
                    t[i*4+0] = v.x; t[i*4+1] = v.y; t[i*4+2] = v.z; t[i*4+3] = v.w;
                }
            }
            #pragma unroll
            for (int jj = 0; jj < CJ; ++jj) {
                const int j = c * CJ + jj;          // compile-time constant
                const float x = t[jj*3+0], y = t[jj*3+1], z = t[jj*3+2];
                const float ang = sqrtf(x*x + y*y + z*z + 1e-12f);
                const float inv = 1.0f / ang;
                const float ux = x*inv, uy = y*inv, uz = z*inv;
                const float s  = __sinf(ang);
                const float cs = __cosf(ang);
                const float ic = 1.0f - cs;
                const float xy = ic*ux*uy, xz = ic*ux*uz, yz = ic*uy*uz;
                const float sx = s*ux, sy = s*uy, sz = s*uz;
                const float R00 = cs + ic*ux*ux, R01 = xy - sz, R02 = xz + sy;
                const float R10 = xy + sz, R11 = cs + ic*uy*uy, R12 = yz - sx;
                const float R20 = xz - sy, R21 = yz + sx, R22 = cs + ic*uz*uz;

                float4 p; float bx, by, bz;
                if (j == 0) {
                    p  = make_float4(w == 0 ? 1.f : 0.f,
                                     w == 1 ? 1.f : 0.f,
                                     w == 2 ? 1.f : 0.f, 0.f);
                    bx = rest_pose[0]; by = rest_pose[1]; bz = rest_pose[2];
                } else {
                    p = rows[PAR[j]];
                    float bf = bone_factor[j - 1];
                    bf = sqrtf(bf*bf + 1e-36f);
                    bx = (rest_pose[j*3+0] - rest_pose[PAR[j]*3+0]) * bf;
                    by = (rest_pose[j*3+1] - rest_pose[PAR[j]*3+1]) * bf;
                    bz = (rest_pose[j*3+2] - rest_pose[PAR[j]*3+2]) * bf;
                }
                float4 nr;
                nr.x = p.x*R00 + p.y*R10 + p.z*R20;
                nr.y = p.x*R01 + p.y*R11 + p.z*R21;
                nr.z = p.x*R02 + p.y*R12 + p.z*R22;
                nr.w = p.x*bx  + p.y*by  + p.z*bz + p.w;
                rows[j] = nr;
                ls[lane * ROW + jj * 4 + w] = nr;
            }
        }
        __syncthreads();

        // ---------- flush (identical to round-3 structure) ----------
        // l2ws: 2048 f4, lane-contiguous
        {
            #pragma unroll
            for (int k = 0; k < 8; ++k) {
                const int g = k * TPB + tid;
                const int i = g >> 5, off = g & 31;
                if (i < n_i)
                    l2g[(size_t)(item0 + i) * 96 + c * 32 + off] = ls[i * ROW + off];
            }
        }
        // orient: 1152 f4 (72 floats / item-chunk)
        {
            #pragma unroll
            for (int k = 0; k < 5; ++k) {
                const int g = k * TPB + tid;
                if (k < 4 || g < IPB * 18) {
                    const int i = g / 18, o4 = g % 18;
                    float v[4];
                    #pragma unroll
                    for (int m = 0; m < 4; ++m) {
                        const int f  = o4 * 4 + m;     // [0,72)
                        const int jj = f / 9, mm = f % 9;
                        const int r  = mm / 3, cc = mm % 3;
                        v[m] = lf[(i * ROW + jj * 4 + r) * 4 + cc];
                    }
                    if (i < n_i)
                        org[(size_t)(item0 + i) * 54 + c * 18 + o4] =
                            make_float4(v[0], v[1], v[2], v[3]);
                }
            }
        }
        // kp3d: 384 f4 (24 floats / item-chunk)
        {
            #pragma unroll
            for (int k = 0; k < 2; ++k) {
                const int g = k * TPB + tid;
                if (k < 1 || g < IPB * 6) {
                    const int i = g / 6, o4 = g % 6;
                    float v[4];
                    #pragma unroll
                    for (int m = 0; m < 4; ++m) {
                        const int f  = o4 * 4 + m;     // [0,24)
                        const int jj = f / 3, r = f % 3;
                        v[m] = lf[(i * ROW + jj * 4 + r) * 4 + 3];
                    }
                    if (i < n_i)
                        kpg[(size_t)(item0 + i) * 18 + c * 6 + o4] =
                            make_float4(v[0], v[1], v[2], v[3]);
                }
            }
        }

        if (c < NCH - 1) __syncthreads();
    }
}

extern "C" void kernel_launch(void* const* d_in, const int* in_sizes, int n_in,
                              void* d_out, int out_size, void* d_ws, size_t ws_size,
                              hipStream_t stream) {
    const float* theta       = (const float*)d_in[0];
    const float* rest_pose   = (const float*)d_in[1];
    const float* bone_factor = (const float*)d_in[2];

    const int Bn = in_sizes[0] / (NJ * 3);
    const size_t BNJ = (size_t)Bn * NJ;

    float* out    = (float*)d_out;
    float* kp3d   = out;                // BNJ*3
    float* orient = out + BNJ * 3;      // BNJ*9
    float* l2ws   = out + BNJ * 12;     // BNJ*16

    const int grid = (Bn + IPB - 1) / IPB;
    fk_kernel<<<grid, TPB, 0, stream>>>(theta, rest_pose, bone_factor,
                                        kp3d, orient, l2ws, Bn);
}

// Round 8
// 91.775 us; speedup vs baseline: 1.3518x; 1.2355x over previous
//
#include <hip/hip_runtime.h>
#include <math.h>

#define NJ   24
#define TPB  256
#define IPB  32     // items per block; whole item written in one phase
#define ST   73     // float4 stride per item in LDS (24*3 + 1 pad)

static constexpr int PAR[NJ] = {-1,0,0,0,1,2,3,4,5,6,7,8,9,9,9,12,13,14,16,17,18,19,20,21};

__global__ __launch_bounds__(TPB, 4) void fk_kernel(
    const float* __restrict__ theta,        // Bn*NJ*3
    const float* __restrict__ rest_pose,    // NJ*3
    const float* __restrict__ bone_factor,  // NJ-1
    float* __restrict__ kp3d,               // Bn*NJ*3
    float* __restrict__ orient,             // Bn*NJ*9
    float* __restrict__ l2ws,               // Bn*NJ*16
    int Bn)
{
    __shared__ float4 ls[IPB * ST];         // 37,376 B -> 4 blocks/CU

    const int tid   = threadIdx.x;
    const int item0 = blockIdx.x * IPB;
    if (item0 >= Bn) return;

    // ---------- compute: lane = (item, row); rows of the affine chain are
    // independent: row_j = row_par(j) * rel_j. 96 active lanes, 24 joints each.
    const int it  = tid / 3;                // item within block (tid<96)
    const int row = tid % 3;
    const int gi  = item0 + it;
    if (tid < 96 && gi < Bn) {
        const float4* th4 = reinterpret_cast<const float4*>(theta) + (size_t)gi * 18;
        float4 rows_[NJ];                   // static-indexed; dead elems pruned
        #pragma unroll
        for (int sub = 0; sub < 3; ++sub) {
            // prefetch this 8-joint window of theta: 6 float4
            float t[24];
            #pragma unroll
            for (int i = 0; i < 6; ++i) {
                const float4 v = th4[sub * 6 + i];
                t[i*4+0] = v.x; t[i*4+1] = v.y; t[i*4+2] = v.z; t[i*4+3] = v.w;
            }
            #pragma unroll
            for (int jj = 0; jj < 8; ++jj) {
                const int j = sub * 8 + jj;             // compile-time constant
                const float x = t[jj*3+0], y = t[jj*3+1], z = t[jj*3+2];
                const float ang = sqrtf(x*x + y*y + z*z + 1e-12f);
                const float inv = 1.0f / ang;
                const float ux = x*inv, uy = y*inv, uz = z*inv;
                const float s  = __sinf(ang);
                const float cs = __cosf(ang);
                const float ic = 1.0f - cs;
                const float xy = ic*ux*uy, xz = ic*ux*uz, yz = ic*uy*uz;
                const float sx = s*ux, sy = s*uy, sz = s*uz;
                const float R00 = cs + ic*ux*ux, R01 = xy - sz, R02 = xz + sy;
                const float R10 = xy + sz, R11 = cs + ic*uy*uy, R12 = yz - sx;
                const float R20 = xz - sy, R21 = yz + sx, R22 = cs + ic*uz*uz;

                float4 p; float bx, by, bz;
                if (j == 0) {
                    p  = make_float4(row == 0 ? 1.f : 0.f,
                                     row == 1 ? 1.f : 0.f,
                                     row == 2 ? 1.f : 0.f, 0.f);
                    bx = rest_pose[0]; by = rest_pose[1]; bz = rest_pose[2];
                } else {
                    p = rows_[PAR[j]];
                    float bf = bone_factor[j - 1];
                    bf = sqrtf(bf*bf + 1e-36f);
                    bx = (rest_pose[j*3+0] - rest_pose[PAR[j]*3+0]) * bf;
                    by = (rest_pose[j*3+1] - rest_pose[PAR[j]*3+1]) * bf;
                    bz = (rest_pose[j*3+2] - rest_pose[PAR[j]*3+2]) * bf;
                }
                float4 nr;
                nr.x = p.x*R00 + p.y*R10 + p.z*R20;
                nr.y = p.x*R01 + p.y*R11 + p.z*R21;
                nr.z = p.x*R02 + p.y*R12 + p.z*R22;
                nr.w = p.x*bx  + p.y*by  + p.z*bz + p.w;
                rows_[j] = nr;
                ls[it * ST + j * 3 + row] = nr;
            }
        }
    }
    __syncthreads();

    // ---------- flush: whole block's outputs, contiguous + aligned, once ----
    const float* lf = reinterpret_cast<const float*>(ls);
    const int n_i = min(IPB, Bn - item0);

    // l2ws: 32 items x 96 f4 = 3072 f4 (48 KB span, 128B-aligned), 12 rounds
    {
        float4* dst = reinterpret_cast<float4*>(l2ws) + (size_t)item0 * 96;
        #pragma unroll
        for (int k = 0; k < 12; ++k) {
            const int q  = k * TPB + tid;          // [0,3072)
            const int i  = q / 96, off = q % 96;
            const int jj = off >> 2, rr = off & 3;
            float4 v;
            if (rr == 3) v = make_float4(0.f, 0.f, 0.f, 1.f);
            else         v = ls[i * ST + jj * 3 + rr];
            if (i < n_i) dst[q] = v;
        }
    }
    // orient: 32 items x 54 f4 = 1728 f4 (27 KB span, aligned), 7 rounds
    {
        float4* dst = reinterpret_cast<float4*>(orient) + (size_t)item0 * 54;
        #pragma unroll
        for (int k = 0; k < 7; ++k) {
            const int q = k * TPB + tid;
            if (k < 6 || q < 1728) {
                float v[4];
                #pragma unroll
                for (int m = 0; m < 4; ++m) {
                    const int f  = q * 4 + m;       // [0,6912)
                    const int i  = f / 216, r2 = f % 216;
                    const int jj = r2 / 9,  mm = r2 % 9;
                    v[m] = lf[(i * ST + jj * 3 + mm / 3) * 4 + mm % 3];
                }
                if (q / 54 < n_i) dst[q] = make_float4(v[0], v[1], v[2], v[3]);
            }
        }
    }
    // kp3d: 32 items x 18 f4 = 576 f4 (9 KB span, aligned), 3 rounds
    {
        float4* dst = reinterpret_cast<float4*>(kp3d) + (size_t)item0 * 18;
        #pragma unroll
        for (int k = 0; k < 3; ++k) {
            const int q = k * TPB + tid;
            if (k < 2 || q < 576) {
                float v[4];
                #pragma unroll
                for (int m = 0; m < 4; ++m) {
                    const int f  = q * 4 + m;       // [0,2304)
                    const int i  = f / 72, r2 = f % 72;
                    const int jj = r2 / 3, rw = r2 % 3;
                    v[m] = lf[(i * ST + jj * 3 + rw) * 4 + 3];
                }
                if (q / 18 < n_i) dst[q] = make_float4(v[0], v[1], v[2], v[3]);
            }
        }
    }
}

extern "C" void kernel_launch(void* const* d_in, const int* in_sizes, int n_in,
                              void* d_out, int out_size, void* d_ws, size_t ws_size,
                              hipStream_t stream) {
    const float* theta       = (const float*)d_in[0];
    const float* rest_pose   = (const float*)d_in[1];
    const float* bone_factor = (const float*)d_in[2];

    const int Bn = in_sizes[0] / (NJ * 3);
    const size_t BNJ = (size_t)Bn * NJ;

    float* out    = (float*)d_out;
    float* kp3d   = out;                // BNJ*3
    float* orient = out + BNJ * 3;      // BNJ*9
    float* l2ws   = out + BNJ * 12;     // BNJ*16

    const int grid = (Bn + IPB - 1) / IPB;
    fk_kernel<<<grid, TPB, 0, stream>>>(theta, rest_pose, bone_factor,
                                        kp3d, orient, l2ws, Bn);
}

// Round 9
// 86.770 us; speedup vs baseline: 1.4297x; 1.0577x over previous
//
#include <hip/hip_runtime.h>
#include <math.h>

#define NJ   24
#define TPB  256
#define IPB  32     // items per block; whole item written in one phase
#define ST   73     // float4 stride per item in LDS (24*3 + 1 pad)

static constexpr int PAR[NJ] = {-1,0,0,0,1,2,3,4,5,6,7,8,9,9,9,12,13,14,16,17,18,19,20,21};

__global__ __launch_bounds__(TPB, 4) void fk_kernel(
    const float* __restrict__ theta,        // Bn*NJ*3
    const float* __restrict__ rest_pose,    // NJ*3
    const float* __restrict__ bone_factor,  // NJ-1
    float* __restrict__ kp3d,               // Bn*NJ*3
    float* __restrict__ orient,             // Bn*NJ*9
    float* __restrict__ l2ws,               // Bn*NJ*16
    int Bn)
{
    __shared__ float4 ls[IPB * ST];         // 37,376 B -> 4 blocks/CU

    const int tid   = threadIdx.x;
    const int item0 = blockIdx.x * IPB;
    if (item0 >= Bn) return;

    // ---------- compute: lane = (item, row); rows of the affine chain are
    // independent: row_j = row_par(j) * rel_j. 96 active lanes, 24 joints each.
    const int it  = tid / 3;                // item within block (tid<96)
    const int row = tid % 3;
    const int gi  = item0 + it;
    if (tid < 96 && gi < Bn) {
        const float4* th4 = reinterpret_cast<const float4*>(theta) + (size_t)gi * 18;
        // ---- single upfront load burst: 18 float4 = whole item's theta.
        // Issued back-to-back; compiler inserts progressive vmcnt waits at the
        // consumption points, so we eat ONE HBM miss latency, not three.
        float4 tv[18];
        #pragma unroll
        for (int i = 0; i < 18; ++i) tv[i] = th4[i];

        float4 rows_[NJ];                   // static-indexed; dead elems pruned
        #pragma unroll
        for (int sub = 0; sub < 3; ++sub) {
            float t[24];                    // unpack window (register renaming)
            #pragma unroll
            for (int i = 0; i < 6; ++i) {
                const float4 v = tv[sub * 6 + i];
                t[i*4+0] = v.x; t[i*4+1] = v.y; t[i*4+2] = v.z; t[i*4+3] = v.w;
            }
            #pragma unroll
            for (int jj = 0; jj < 8; ++jj) {
                const int j = sub * 8 + jj;             // compile-time constant
                const float x = t[jj*3+0], y = t[jj*3+1], z = t[jj*3+2];
                const float ang = sqrtf(x*x + y*y + z*z + 1e-12f);
                const float inv = 1.0f / ang;
                const float ux = x*inv, uy = y*inv, uz = z*inv;
                const float s  = __sinf(ang);
                const float cs = __cosf(ang);
                const float ic = 1.0f - cs;
                const float xy = ic*ux*uy, xz = ic*ux*uz, yz = ic*uy*uz;
                const float sx = s*ux, sy = s*uy, sz = s*uz;
                const float R00 = cs + ic*ux*ux, R01 = xy - sz, R02 = xz + sy;
                const float R10 = xy + sz, R11 = cs + ic*uy*uy, R12 = yz - sx;
                const float R20 = xz - sy, R21 = yz + sx, R22 = cs + ic*uz*uz;

                float4 p; float bx, by, bz;
                if (j == 0) {
                    p  = make_float4(row == 0 ? 1.f : 0.f,
                                     row == 1 ? 1.f : 0.f,
                                     row == 2 ? 1.f : 0.f, 0.f);
                    bx = rest_pose[0]; by = rest_pose[1]; bz = rest_pose[2];
                } else {
                    p = rows_[PAR[j]];
                    float bf = bone_factor[j - 1];
                    bf = sqrtf(bf*bf + 1e-36f);
                    bx = (rest_pose[j*3+0] - rest_pose[PAR[j]*3+0]) * bf;
                    by = (rest_pose[j*3+1] - rest_pose[PAR[j]*3+1]) * bf;
                    bz = (rest_pose[j*3+2] - rest_pose[PAR[j]*3+2]) * bf;
                }
                float4 nr;
                nr.x = p.x*R00 + p.y*R10 + p.z*R20;
                nr.y = p.x*R01 + p.y*R11 + p.z*R21;
                nr.z = p.x*R02 + p.y*R12 + p.z*R22;
                nr.w = p.x*bx  + p.y*by  + p.z*bz + p.w;
                rows_[j] = nr;
                ls[it * ST + j * 3 + row] = nr;
            }
        }
    }
    __syncthreads();

    // ---------- flush: whole block's outputs, contiguous + aligned, once ----
    const float* lf = reinterpret_cast<const float*>(ls);
    const int n_i = min(IPB, Bn - item0);

    // l2ws: 32 items x 96 f4 = 3072 f4 (48 KB span, 128B-aligned), 12 rounds
    {
        float4* dst = reinterpret_cast<float4*>(l2ws) + (size_t)item0 * 96;
        #pragma unroll
        for (int k = 0; k < 12; ++k) {
            const int q  = k * TPB + tid;          // [0,3072)
            const int i  = q / 96, off = q % 96;
            const int jj = off >> 2, rr = off & 3;
            float4 v;
            if (rr == 3) v = make_float4(0.f, 0.f, 0.f, 1.f);
            else         v = ls[i * ST + jj * 3 + rr];
            if (i < n_i) dst[q] = v;
        }
    }
    // orient: 32 items x 54 f4 = 1728 f4 (27 KB span, aligned), 7 rounds
    {
        float4* dst = reinterpret_cast<float4*>(orient) + (size_t)item0 * 54;
        #pragma unroll
        for (int k = 0; k < 7; ++k) {
            const int q = k * TPB + tid;
            if (k < 6 || q < 1728) {
                float v[4];
                #pragma unroll
                for (int m = 0; m < 4; ++m) {
                    const int f  = q * 4 + m;       // [0,6912)
                    const int i  = f / 216, r2 = f % 216;
                    const int jj = r2 / 9,  mm = r2 % 9;
                    v[m] = lf[(i * ST + jj * 3 + mm / 3) * 4 + mm % 3];
                }
                if (q / 54 < n_i) dst[q] = make_float4(v[0], v[1], v[2], v[3]);
            }
        }
    }
    // kp3d: 32 items x 18 f4 = 576 f4 (9 KB span, aligned), 3 rounds
    {
        float4* dst = reinterpret_cast<float4*>(kp3d) + (size_t)item0 * 18;
        #pragma unroll
        for (int k = 0; k < 3; ++k) {
            const int q = k * TPB + tid;
            if (k < 2 || q < 576) {
                float v[4];
                #pragma unroll
                for (int m = 0; m < 4; ++m) {
                    const int f  = q * 4 + m;       // [0,2304)
                    const int i  = f / 72, r2 = f % 72;
                    const int jj = r2 / 3, rw = r2 % 3;
                    v[m] = lf[(i * ST + jj * 3 + rw) * 4 + 3];
                }
                if (q / 18 < n_i) dst[q] = make_float4(v[0], v[1], v[2], v[3]);
            }
        }
    }
}

extern "C" void kernel_launch(void* const* d_in, const int* in_sizes, int n_in,
                              void* d_out, int out_size, void* d_ws, size_t ws_size,
                              hipStream_t stream) {
    const float* theta       = (const float*)d_in[0];
    const float* rest_pose   = (const float*)d_in[1];
    const float* bone_factor = (const float*)d_in[2];

    const int Bn = in_sizes[0] / (NJ * 3);
    const size_t BNJ = (size_t)Bn * NJ;

    float* out    = (float*)d_out;
    float* kp3d   = out;                // BNJ*3
    float* orient = out + BNJ * 3;      // BNJ*9
    float* l2ws   = out + BNJ * 12;     // BNJ*16

    const int grid = (Bn + IPB - 1) / IPB;
    fk_kernel<<<grid, TPB, 0, stream>>>(theta, rest_pose, bone_factor,
                                        kp3d, orient, l2ws, Bn);
}